// Round 1
// 1283.181 us; speedup vs baseline: 1.0144x; 1.0144x over previous
//
#include <hip/hip_runtime.h>
#include <stdint.h>

typedef __bf16 bf16;
typedef __attribute__((ext_vector_type(8))) __bf16 bf16x8;
typedef __attribute__((ext_vector_type(4))) __bf16 bf16x4;
typedef __attribute__((ext_vector_type(4))) float f32x4;

#define T_TOK 4096
#define DIM   1536
#define NE    64
#define HD    384
#define TOPK  8
#define CAP   1024
#define TK    32768   // T_TOK*TOPK

// ---------------- fused router: fp32 logits -> softmax -> top8 -> renorm ----------------
__global__ __launch_bounds__(256) void router_k(const float* __restrict__ x, const float* __restrict__ gw,
                                                int* __restrict__ sel, float* __restrict__ wts,
                                                int* __restrict__ counts) {
    __shared__ float xs[16][DIM];     // 98304 B
    __shared__ float lgs[16][NE];     // 4096 B
    int t0 = blockIdx.x * 16;
    int tid = threadIdx.x;
    {
        const float4* src = (const float4*)(x + (size_t)t0 * DIM);
        float4* dst = (float4*)&xs[0][0];
        for (int i = tid; i < 16 * DIM / 4; i += 256) dst[i] = src[i];
    }
    __syncthreads();
    int lane = tid & 63, wv = tid >> 6;
    for (int ee = 0; ee < 16; ++ee) {
        int e = wv * 16 + ee;
        const float2* g2 = (const float2*)(gw + (size_t)e * DIM);
        float acc[16];
        #pragma unroll
        for (int t = 0; t < 16; ++t) acc[t] = 0.f;
        #pragma unroll
        for (int it = 0; it < DIM / 128; ++it) {
            float2 gv = g2[lane + 64 * it];
            #pragma unroll
            for (int t = 0; t < 16; ++t) {
                float2 xv = *(const float2*)&xs[t][2 * (lane + 64 * it)];
                acc[t] += gv.x * xv.x + gv.y * xv.y;
            }
        }
        #pragma unroll
        for (int t = 0; t < 16; ++t) {
            float a = acc[t];
            #pragma unroll
            for (int off = 32; off; off >>= 1) a += __shfl_xor(a, off, 64);
            if (lane == 0) lgs[t][e] = a;
        }
    }
    __syncthreads();
    for (int q = 0; q < 4; ++q) {
        int tt = wv * 4 + q;
        int t = t0 + tt;
        float l = lgs[tt][lane];
        float m = l;
        #pragma unroll
        for (int off = 32; off; off >>= 1) m = fmaxf(m, __shfl_xor(m, off, 64));
        float p = __expf(l - m);
        float s = p;
        #pragma unroll
        for (int off = 32; off; off >>= 1) s += __shfl_xor(s, off, 64);
        p /= s;
        float cur = p;
        float psum = 0.f;
        float myv = 0.f; int myi = 0;
        #pragma unroll
        for (int k = 0; k < 8; ++k) {
            float v = cur; int idx = lane;
            #pragma unroll
            for (int off = 32; off; off >>= 1) {
                float ov = __shfl_xor(v, off, 64);
                int   oi = __shfl_xor(idx, off, 64);
                if (ov > v || (ov == v && oi < idx)) { v = ov; idx = oi; }
            }
            psum += v;
            if (lane == k) { myv = v; myi = idx; }
            if (lane == idx) cur = -1.f;
        }
        if (lane < 8) {
            sel[t * TOPK + lane] = myi;
            wts[t * TOPK + lane] = myv / psum;
            atomicAdd(&counts[myi], 1);
        }
    }
}

// ---------------- exclusive scan over 64 counts (capped at CAP) ----------------
__global__ void scan_k(const int* __restrict__ counts, int* __restrict__ offsets) {
    if (threadIdx.x == 0) {
        int s = 0;
        for (int e = 0; e < NE; ++e) {
            offsets[e] = s;
            int c = counts[e]; if (c > CAP) c = CAP;
            s += c;
        }
        offsets[NE] = s;
    }
}

// ---------------- compact assignments by expert ----------------
__global__ __launch_bounds__(256) void dispatch_k(const int* __restrict__ sel, const float* __restrict__ wts,
                                                  const int* __restrict__ offsets, int* __restrict__ cursor,
                                                  int* __restrict__ rowtok, float* __restrict__ roww) {
    int i = blockIdx.x * 256 + threadIdx.x;
    if (i >= TK) return;
    int e = sel[i];
    int t = i >> 3;
    int p = atomicAdd(&cursor[e], 1);
    if (p < CAP) {
        int idx = offsets[e] + p;
        rowtok[idx] = t;
        roww[idx] = wts[i];
    }
}

// ---------------- prep: x fp32 -> bf16 ----------------
__global__ __launch_bounds__(256) void xconv_k(const float* __restrict__ in, bf16* __restrict__ out) {
    int i = blockIdx.x * 256 + threadIdx.x;
    float4 a = *(const float4*)(in + (size_t)i * 8);
    float4 b = *(const float4*)(in + (size_t)i * 8 + 4);
    bf16x8 v;
    v[0] = (bf16)a.x; v[1] = (bf16)a.y; v[2] = (bf16)a.z; v[3] = (bf16)a.w;
    v[4] = (bf16)b.x; v[5] = (bf16)b.y; v[6] = (bf16)b.z; v[7] = (bf16)b.w;
    *(bf16x8*)(out + (size_t)i * 8) = v;
}

// ---------------- prep: per-expert transpose + convert: in [E][R][C] f32 -> out [E][C][R] bf16 ----------------
__global__ __launch_bounds__(256) void tconv_k(const float* __restrict__ in, bf16* __restrict__ out, int R, int C) {
    __shared__ float tile[64][65];
    int e = blockIdx.z;
    int r0 = blockIdx.x * 64, c0 = blockIdx.y * 64;
    int t = threadIdx.x;
    int rr = t >> 4, cc = (t & 15) * 4;
    const float* src = in + ((size_t)e * R + r0) * C + c0;
    #pragma unroll
    for (int j = 0; j < 4; ++j) {
        float4 v = *(const float4*)(src + (size_t)(rr + 16 * j) * C + cc);
        tile[rr + 16 * j][cc + 0] = v.x;
        tile[rr + 16 * j][cc + 1] = v.y;
        tile[rr + 16 * j][cc + 2] = v.z;
        tile[rr + 16 * j][cc + 3] = v.w;
    }
    __syncthreads();
    bf16* dst = out + ((size_t)e * C + c0) * R + r0;
    #pragma unroll
    for (int j = 0; j < 4; ++j) {
        int oc = rr + 16 * j;   // row of output tile = original column
        bf16x4 v;
        v[0] = (bf16)tile[cc + 0][oc];
        v[1] = (bf16)tile[cc + 1][oc];
        v[2] = (bf16)tile[cc + 2][oc];
        v[3] = (bf16)tile[cc + 3][oc];
        *(bf16x4*)(dst + (size_t)oc * R + cc) = v;
    }
}

// ---------------- async global->LDS helper (16B per lane, dest = wave-uniform base + lane*16) ----------------
__device__ __forceinline__ void gll16(const bf16* g, bf16* l) {
    __builtin_amdgcn_global_load_lds((const __attribute__((address_space(1))) void*)g,
                                     (__attribute__((address_space(3))) void*)l, 16, 0, 0);
}

// ---------------- GEMM1 (new): fused gate+up, all-bf16, global_load_lds staging ----------------
// grid (8 mtiles, 3 ntiles, 64 experts), block 256 (4 waves, each 64x64 out)
__global__ __launch_bounds__(256) void gemm_gu2_k(
        const bf16* __restrict__ xb, const bf16* __restrict__ WgT, const bf16* __restrict__ WuT,
        const int* __restrict__ rowtok, const int* __restrict__ offsets, const int* __restrict__ counts,
        bf16* __restrict__ Abuf) {
    int e = blockIdx.z;
    int cnt = counts[e]; if (cnt > CAP) cnt = CAP;
    int m0 = blockIdx.x * 128;
    if (cnt == 0 || m0 >= cnt) return;
    int base = offsets[e];
    int n0 = blockIdx.y * 128;

    __shared__ __align__(16) bf16 As[128 * 32];
    __shared__ __align__(16) bf16 Bgs[128 * 32];
    __shared__ __align__(16) bf16 Bus[128 * 32];

    int tid = threadIdx.x, lane = tid & 63, wv = tid >> 6;

    // staging geometry: LDS tile is linear [128 rows][32 k] bf16 (64 B/row).
    // wave wv, issue i covers rows half*16..half*16+15 (half = wv*2+i); lane l -> row half*16+(l>>2), k-seg (l&3)*8.
    const bf16 *pa[2], *pg[2], *pu[2];
    bf16 *la[2], *lg[2], *lu[2];
    #pragma unroll
    for (int i = 0; i < 2; ++i) {
        int half = wv * 2 + i;
        int row  = half * 16 + (lane >> 2);
        int ks   = (lane & 3) * 8;
        int mr = m0 + row; if (mr >= cnt) mr = cnt - 1;
        pa[i] = xb  + (size_t)rowtok[base + mr] * DIM + ks;
        pg[i] = WgT + ((size_t)e * HD + n0 + row) * DIM + ks;
        pu[i] = WuT + ((size_t)e * HD + n0 + row) * DIM + ks;
        la[i] = &As[half * 512];
        lg[i] = &Bgs[half * 512];
        lu[i] = &Bus[half * 512];
    }

    int mo = (wv & 1) * 64, no = (wv >> 1) * 64;
    int fr = lane & 15, fq = lane >> 4;

    f32x4 ag[4][4], au[4][4];
    #pragma unroll
    for (int i = 0; i < 4; ++i)
        #pragma unroll
        for (int j = 0; j < 4; ++j)
            #pragma unroll
            for (int r = 0; r < 4; ++r) { ag[i][j][r] = 0.f; au[i][j][r] = 0.f; }

    for (int k0 = 0; k0 < DIM; k0 += 32) {
        #pragma unroll
        for (int i = 0; i < 2; ++i) {
            gll16(pa[i] + k0, la[i]);
            gll16(pg[i] + k0, lg[i]);
            gll16(pu[i] + k0, lu[i]);
        }
        __syncthreads();   // drains vmcnt -> tile ready
        bf16x8 af[4], bgf[4], buf_[4];
        #pragma unroll
        for (int i = 0; i < 4; ++i) {
            af[i]   = *(const bf16x8*)&As[(mo + i * 16 + fr) * 32 + fq * 8];
            bgf[i]  = *(const bf16x8*)&Bgs[(no + i * 16 + fr) * 32 + fq * 8];
            buf_[i] = *(const bf16x8*)&Bus[(no + i * 16 + fr) * 32 + fq * 8];
        }
        #pragma unroll
        for (int i = 0; i < 4; ++i)
            #pragma unroll
            for (int j = 0; j < 4; ++j) {
                ag[i][j] = __builtin_amdgcn_mfma_f32_16x16x32_bf16(af[i], bgf[j], ag[i][j], 0, 0, 0);
                au[i][j] = __builtin_amdgcn_mfma_f32_16x16x32_bf16(af[i], buf_[j], au[i][j], 0, 0, 0);
            }
        __syncthreads();   // protect LDS reuse next iter
    }
    #pragma unroll
    for (int i = 0; i < 4; ++i) {
        #pragma unroll
        for (int j = 0; j < 4; ++j) {
            int col = n0 + no + j * 16 + fr;
            #pragma unroll
            for (int r = 0; r < 4; ++r) {
                int gm = m0 + mo + i * 16 + fq * 4 + r;
                if (gm < cnt) {
                    float g = ag[i][j][r], u = au[i][j][r];
                    float sg = g / (1.f + __expf(-g));   // silu
                    Abuf[(size_t)(base + gm) * HD + col] = (bf16)(sg * u);
                }
            }
        }
    }
}

// ---------------- GEMM2 (new): down projection, all-bf16, global_load_lds staging ----------------
// grid (8 mtiles, 12 ntiles, 64 experts)
__global__ __launch_bounds__(256) void gemm_dn2_k(
        const bf16* __restrict__ Abuf, const bf16* __restrict__ WdT,
        const int* __restrict__ rowtok, const float* __restrict__ roww,
        const int* __restrict__ offsets, const int* __restrict__ counts,
        float* __restrict__ out) {
    int e = blockIdx.z;
    int cnt = counts[e]; if (cnt > CAP) cnt = CAP;
    int m0 = blockIdx.x * 128;
    if (cnt == 0 || m0 >= cnt) return;
    int base = offsets[e];
    int n0 = blockIdx.y * 128;

    __shared__ __align__(16) bf16 As[128 * 32];
    __shared__ __align__(16) bf16 Bs[128 * 32];

    int tid = threadIdx.x, lane = tid & 63, wv = tid >> 6;
    const bf16 *pa[2], *pb[2];
    bf16 *la[2], *lb[2];
    #pragma unroll
    for (int i = 0; i < 2; ++i) {
        int half = wv * 2 + i;
        int row  = half * 16 + (lane >> 2);
        int ks   = (lane & 3) * 8;
        int mr = m0 + row; if (mr >= cnt) mr = cnt - 1;
        pa[i] = Abuf + (size_t)(base + mr) * HD + ks;
        pb[i] = WdT  + ((size_t)e * DIM + n0 + row) * HD + ks;
        la[i] = &As[half * 512];
        lb[i] = &Bs[half * 512];
    }

    int mo = (wv & 1) * 64, no = (wv >> 1) * 64;
    int fr = lane & 15, fq = lane >> 4;

    f32x4 acc[4][4];
    #pragma unroll
    for (int i = 0; i < 4; ++i)
        #pragma unroll
        for (int j = 0; j < 4; ++j)
            #pragma unroll
            for (int r = 0; r < 4; ++r) acc[i][j][r] = 0.f;

    for (int k0 = 0; k0 < HD; k0 += 32) {
        #pragma unroll
        for (int i = 0; i < 2; ++i) {
            gll16(pa[i] + k0, la[i]);
            gll16(pb[i] + k0, lb[i]);
        }
        __syncthreads();
        bf16x8 af[4], bf[4];
        #pragma unroll
        for (int i = 0; i < 4; ++i) {
            af[i] = *(const bf16x8*)&As[(mo + i * 16 + fr) * 32 + fq * 8];
            bf[i] = *(const bf16x8*)&Bs[(no + i * 16 + fr) * 32 + fq * 8];
        }
        #pragma unroll
        for (int i = 0; i < 4; ++i)
            #pragma unroll
            for (int j = 0; j < 4; ++j)
                acc[i][j] = __builtin_amdgcn_mfma_f32_16x16x32_bf16(af[i], bf[j], acc[i][j], 0, 0, 0);
        __syncthreads();
    }
    #pragma unroll
    for (int i = 0; i < 4; ++i) {
        #pragma unroll
        for (int r = 0; r < 4; ++r) {
            int gm = m0 + mo + i * 16 + fq * 4 + r;
            if (gm < cnt) {
                int tok = rowtok[base + gm];
                float w = roww[base + gm];
                float* po = out + (size_t)tok * DIM + n0 + no + fr;
                #pragma unroll
                for (int j = 0; j < 4; ++j)
                    atomicAdd(po + j * 16, acc[i][j][r] * w);
            }
        }
    }
}

// ================= fallback path (old fp32-staging kernels) — used if workspace too small =================
__device__ __forceinline__ bf16x8 pack8(const float* f) {
    bf16x8 v;
    #pragma unroll
    for (int j = 0; j < 8; ++j) v[j] = (bf16)f[j];
    return v;
}

__global__ __launch_bounds__(256) void gemm_gu_k(
        const float* __restrict__ x, const float* __restrict__ Wg, const float* __restrict__ Wu,
        const int* __restrict__ rowtok, const int* __restrict__ offsets, const int* __restrict__ counts,
        bf16* __restrict__ Abuf) {
    int e = blockIdx.z;
    int cnt = counts[e]; if (cnt > CAP) cnt = CAP;
    int m0 = blockIdx.x * 128;
    if (cnt == 0 || m0 >= cnt) return;
    int base = offsets[e];
    int n0 = blockIdx.y * 128;

    __shared__ __align__(16) bf16 As[128 * 32];
    __shared__ __align__(16) bf16 Bgs[128 * 32];
    __shared__ __align__(16) bf16 Bus[128 * 32];

    int tid = threadIdx.x;
    int arow = tid >> 1, aseg = (tid & 1) * 16;
    int mrow = m0 + arow; if (mrow >= cnt) mrow = cnt - 1;
    const float* pA = x + (size_t)rowtok[base + mrow] * DIM + aseg;
    int bn = tid & 127;
    int bk = (tid >> 7) * 16;
    const float* pG = Wg + ((size_t)e * DIM + bk) * HD + (n0 + bn);
    const float* pU = Wu + ((size_t)e * DIM + bk) * HD + (n0 + bn);

    int lane = tid & 63, wv = tid >> 6;
    int mo = (wv & 1) * 64, no = (wv >> 1) * 64;
    int fr = lane & 15, fq = lane >> 4;

    f32x4 ag[4][4], au[4][4];
    #pragma unroll
    for (int i = 0; i < 4; ++i)
        #pragma unroll
        for (int j = 0; j < 4; ++j)
            #pragma unroll
            for (int r = 0; r < 4; ++r) { ag[i][j][r] = 0.f; au[i][j][r] = 0.f; }

    for (int k0 = 0; k0 < DIM; k0 += 32) {
        float av[16] __attribute__((aligned(16)));
        float gv[16] __attribute__((aligned(16)));
        float uv[16] __attribute__((aligned(16)));
        *(float4*)&av[0]  = *(const float4*)(pA + k0);
        *(float4*)&av[4]  = *(const float4*)(pA + k0 + 4);
        *(float4*)&av[8]  = *(const float4*)(pA + k0 + 8);
        *(float4*)&av[12] = *(const float4*)(pA + k0 + 12);
        #pragma unroll
        for (int j = 0; j < 16; ++j) {
            gv[j] = pG[(size_t)(k0 + j) * HD];
            uv[j] = pU[(size_t)(k0 + j) * HD];
        }
        __syncthreads();
        *(bf16x8*)&As[arow * 32 + aseg]      = pack8(&av[0]);
        *(bf16x8*)&As[arow * 32 + aseg + 8]  = pack8(&av[8]);
        *(bf16x8*)&Bgs[bn * 32 + bk]         = pack8(&gv[0]);
        *(bf16x8*)&Bgs[bn * 32 + bk + 8]     = pack8(&gv[8]);
        *(bf16x8*)&Bus[bn * 32 + bk]         = pack8(&uv[0]);
        *(bf16x8*)&Bus[bn * 32 + bk + 8]     = pack8(&uv[8]);
        __syncthreads();
        bf16x8 af[4], bgf[4], buf_[4];
        #pragma unroll
        for (int i = 0; i < 4; ++i) {
            af[i]   = *(const bf16x8*)&As[(mo + i * 16 + fr) * 32 + fq * 8];
            bgf[i]  = *(const bf16x8*)&Bgs[(no + i * 16 + fr) * 32 + fq * 8];
            buf_[i] = *(const bf16x8*)&Bus[(no + i * 16 + fr) * 32 + fq * 8];
        }
        #pragma unroll
        for (int i = 0; i < 4; ++i)
            #pragma unroll
            for (int j = 0; j < 4; ++j) {
                ag[i][j] = __builtin_amdgcn_mfma_f32_16x16x32_bf16(af[i], bgf[j], ag[i][j], 0, 0, 0);
                au[i][j] = __builtin_amdgcn_mfma_f32_16x16x32_bf16(af[i], buf_[j], au[i][j], 0, 0, 0);
            }
    }
    #pragma unroll
    for (int i = 0; i < 4; ++i) {
        #pragma unroll
        for (int j = 0; j < 4; ++j) {
            int col = n0 + no + j * 16 + fr;
            #pragma unroll
            for (int r = 0; r < 4; ++r) {
                int gm = m0 + mo + i * 16 + fq * 4 + r;
                if (gm < cnt) {
                    float g = ag[i][j][r], u = au[i][j][r];
                    float sg = g / (1.f + __expf(-g));
                    Abuf[(size_t)(base + gm) * HD + col] = (bf16)(sg * u);
                }
            }
        }
    }
}

__global__ __launch_bounds__(256) void gemm_dn_k(
        const bf16* __restrict__ Abuf, const float* __restrict__ Wd,
        const int* __restrict__ rowtok, const float* __restrict__ roww,
        const int* __restrict__ offsets, const int* __restrict__ counts,
        float* __restrict__ out) {
    int e = blockIdx.z;
    int cnt = counts[e]; if (cnt > CAP) cnt = CAP;
    int m0 = blockIdx.x * 128;
    if (cnt == 0 || m0 >= cnt) return;
    int base = offsets[e];
    int n0 = blockIdx.y * 128;

    __shared__ __align__(16) bf16 As[128 * 32];
    __shared__ __align__(16) bf16 Bs[128 * 32];

    int tid = threadIdx.x;
    int arow = tid >> 1, aseg = (tid & 1) * 16;
    int mrow = m0 + arow; if (mrow >= cnt) mrow = cnt - 1;
    const bf16* pA = Abuf + (size_t)(base + mrow) * HD + aseg;
    int bn = tid & 127;
    int bk = (tid >> 7) * 16;
    const float* pB = Wd + ((size_t)e * HD + bk) * DIM + (n0 + bn);

    int lane = tid & 63, wv = tid >> 6;
    int mo = (wv & 1) * 64, no = (wv >> 1) * 64;
    int fr = lane & 15, fq = lane >> 4;

    f32x4 acc[4][4];
    #pragma unroll
    for (int i = 0; i < 4; ++i)
        #pragma unroll
        for (int j = 0; j < 4; ++j)
            #pragma unroll
            for (int r = 0; r < 4; ++r) acc[i][j][r] = 0.f;

    for (int k0 = 0; k0 < HD; k0 += 32) {
        uint4 a0 = *(const uint4*)(pA + k0);
        uint4 a1 = *(const uint4*)(pA + k0 + 8);
        float bv[16] __attribute__((aligned(16)));
        #pragma unroll
        for (int j = 0; j < 16; ++j) bv[j] = pB[(size_t)(k0 + j) * DIM];
        __syncthreads();
        *(uint4*)&As[arow * 32 + aseg]     = a0;
        *(uint4*)&As[arow * 32 + aseg + 8] = a1;
        *(bf16x8*)&Bs[bn * 32 + bk]     = pack8(&bv[0]);
        *(bf16x8*)&Bs[bn * 32 + bk + 8] = pack8(&bv[8]);
        __syncthreads();
        bf16x8 af[4], bf[4];
        #pragma unroll
        for (int i = 0; i < 4; ++i) {
            af[i] = *(const bf16x8*)&As[(mo + i * 16 + fr) * 32 + fq * 8];
            bf[i] = *(const bf16x8*)&Bs[(no + i * 16 + fr) * 32 + fq * 8];
        }
        #pragma unroll
        for (int i = 0; i < 4; ++i)
            #pragma unroll
            for (int j = 0; j < 4; ++j)
                acc[i][j] = __builtin_amdgcn_mfma_f32_16x16x32_bf16(af[i], bf[j], acc[i][j], 0, 0, 0);
    }
    #pragma unroll
    for (int i = 0; i < 4; ++i) {
        #pragma unroll
        for (int r = 0; r < 4; ++r) {
            int gm = m0 + mo + i * 16 + fq * 4 + r;
            if (gm < cnt) {
                int tok = rowtok[base + gm];
                float w = roww[base + gm];
                float* po = out + (size_t)tok * DIM + n0 + no + fr;
                #pragma unroll
                for (int j = 0; j < 4; ++j)
                    atomicAdd(po + j * 16, acc[i][j][r] * w);
            }
        }
    }
}

extern "C" void kernel_launch(void* const* d_in, const int* in_sizes, int n_in,
                              void* d_out, int out_size, void* d_ws, size_t ws_size,
                              hipStream_t stream) {
    const float* x  = (const float*)d_in[0];
    const float* gw = (const float*)d_in[1];
    const float* Wg = (const float*)d_in[2];
    const float* Wu = (const float*)d_in[3];
    const float* Wd = (const float*)d_in[4];
    float* out = (float*)d_out;
    char* ws = (char*)d_ws;

    int*   counts  = (int*)(ws + 0);        // 64 ints
    int*   cursor  = (int*)(ws + 256);      // 64 ints
    int*   offsets = (int*)(ws + 512);      // 65 ints
    int*   sel     = (int*)(ws + 4096);                    // TK ints
    float* wts     = (float*)(ws + 4096 + 1 * 131072);
    int*   rowtok  = (int*)(ws + 4096 + 2 * 131072);
    float* roww    = (float*)(ws + 4096 + 3 * 131072);
    bf16*  AbufOld = (bf16*)(ws + 4096 + 4 * 131072);      // fallback layout (25.2 MB)

    // big-workspace layout for the bf16 fast path
    size_t o = (size_t)1 << 20;
    bf16* Abuf = (bf16*)(ws + o); o += (size_t)TK * HD * 2;         // 25.2 MB
    bf16* xb   = (bf16*)(ws + o); o += (size_t)T_TOK * DIM * 2;     // 12.6 MB
    bf16* WgT  = (bf16*)(ws + o); o += (size_t)NE * HD * DIM * 2;   // 75.5 MB
    bf16* WuT  = (bf16*)(ws + o); o += (size_t)NE * HD * DIM * 2;   // 75.5 MB
    bf16* WdT  = (bf16*)(ws + o); o += (size_t)NE * DIM * HD * 2;   // 75.5 MB
    bool big = ws_size >= o;                                        // ~265.3 MB

    hipMemsetAsync(ws, 0, 1024, stream);
    hipMemsetAsync(d_out, 0, (size_t)out_size * sizeof(float), stream);
    router_k<<<T_TOK / 16, 256, 0, stream>>>(x, gw, sel, wts, counts);
    scan_k<<<1, 64, 0, stream>>>(counts, offsets);
    dispatch_k<<<TK / 256, 256, 0, stream>>>(sel, wts, offsets, cursor, rowtok, roww);

    if (big) {
        xconv_k<<<(T_TOK * DIM / 8) / 256, 256, 0, stream>>>(x, xb);
        tconv_k<<<dim3(DIM / 64, HD / 64, NE), 256, 0, stream>>>(Wg, WgT, DIM, HD);
        tconv_k<<<dim3(DIM / 64, HD / 64, NE), 256, 0, stream>>>(Wu, WuT, DIM, HD);
        tconv_k<<<dim3(HD / 64, DIM / 64, NE), 256, 0, stream>>>(Wd, WdT, HD, DIM);
        gemm_gu2_k<<<dim3(CAP / 128, HD / 128, NE), 256, 0, stream>>>(xb, WgT, WuT, rowtok, offsets, counts, Abuf);
        gemm_dn2_k<<<dim3(CAP / 128, DIM / 128, NE), 256, 0, stream>>>(Abuf, WdT, rowtok, roww, offsets, counts, out);
    } else {
        gemm_gu_k<<<dim3(CAP / 128, HD / 128, NE), 256, 0, stream>>>(x, Wg, Wu, rowtok, offsets, AbufOld == Abuf ? counts : counts, AbufOld);
        gemm_dn_k<<<dim3(CAP / 128, DIM / 128, NE), 256, 0, stream>>>(AbufOld, Wd, rowtok, roww, offsets, counts, out);
    }
}

// Round 2
// 1093.866 us; speedup vs baseline: 1.1900x; 1.1731x over previous
//
#include <hip/hip_runtime.h>
#include <stdint.h>

typedef __bf16 bf16;
typedef __attribute__((ext_vector_type(8))) __bf16 bf16x8;
typedef __attribute__((ext_vector_type(4))) __bf16 bf16x4;
typedef __attribute__((ext_vector_type(4))) float f32x4;

#define T_TOK 4096
#define DIM   1536
#define NE    64
#define HD    384
#define TOPK  8
#define CAP   1024
#define TK    32768   // T_TOK*TOPK

// ---------------- fused router: fp32 logits -> softmax -> top8 -> renorm ----------------
__global__ __launch_bounds__(256) void router_k(const float* __restrict__ x, const float* __restrict__ gw,
                                                int* __restrict__ sel, float* __restrict__ wts,
                                                int* __restrict__ counts) {
    __shared__ float xs[16][DIM];     // 98304 B
    __shared__ float lgs[16][NE];     // 4096 B
    int t0 = blockIdx.x * 16;
    int tid = threadIdx.x;
    {
        const float4* src = (const float4*)(x + (size_t)t0 * DIM);
        float4* dst = (float4*)&xs[0][0];
        for (int i = tid; i < 16 * DIM / 4; i += 256) dst[i] = src[i];
    }
    __syncthreads();
    int lane = tid & 63, wv = tid >> 6;
    for (int ee = 0; ee < 16; ++ee) {
        int e = wv * 16 + ee;
        const float2* g2 = (const float2*)(gw + (size_t)e * DIM);
        float acc[16];
        #pragma unroll
        for (int t = 0; t < 16; ++t) acc[t] = 0.f;
        #pragma unroll
        for (int it = 0; it < DIM / 128; ++it) {
            float2 gv = g2[lane + 64 * it];
            #pragma unroll
            for (int t = 0; t < 16; ++t) {
                float2 xv = *(const float2*)&xs[t][2 * (lane + 64 * it)];
                acc[t] += gv.x * xv.x + gv.y * xv.y;
            }
        }
        #pragma unroll
        for (int t = 0; t < 16; ++t) {
            float a = acc[t];
            #pragma unroll
            for (int off = 32; off; off >>= 1) a += __shfl_xor(a, off, 64);
            if (lane == 0) lgs[t][e] = a;
        }
    }
    __syncthreads();
    for (int q = 0; q < 4; ++q) {
        int tt = wv * 4 + q;
        int t = t0 + tt;
        float l = lgs[tt][lane];
        float m = l;
        #pragma unroll
        for (int off = 32; off; off >>= 1) m = fmaxf(m, __shfl_xor(m, off, 64));
        float p = __expf(l - m);
        float s = p;
        #pragma unroll
        for (int off = 32; off; off >>= 1) s += __shfl_xor(s, off, 64);
        p /= s;
        float cur = p;
        float psum = 0.f;
        float myv = 0.f; int myi = 0;
        #pragma unroll
        for (int k = 0; k < 8; ++k) {
            float v = cur; int idx = lane;
            #pragma unroll
            for (int off = 32; off; off >>= 1) {
                float ov = __shfl_xor(v, off, 64);
                int   oi = __shfl_xor(idx, off, 64);
                if (ov > v || (ov == v && oi < idx)) { v = ov; idx = oi; }
            }
            psum += v;
            if (lane == k) { myv = v; myi = idx; }
            if (lane == idx) cur = -1.f;
        }
        if (lane < 8) {
            sel[t * TOPK + lane] = myi;
            wts[t * TOPK + lane] = myv / psum;
            atomicAdd(&counts[myi], 1);
        }
    }
}

// ---------------- exclusive scan over 64 counts (capped at CAP) ----------------
__global__ void scan_k(const int* __restrict__ counts, int* __restrict__ offsets) {
    if (threadIdx.x == 0) {
        int s = 0;
        for (int e = 0; e < NE; ++e) {
            offsets[e] = s;
            int c = counts[e]; if (c > CAP) c = CAP;
            s += c;
        }
        offsets[NE] = s;
    }
}

// ---------------- compact assignments by expert ----------------
__global__ __launch_bounds__(256) void dispatch_k(const int* __restrict__ sel, const float* __restrict__ wts,
                                                  const int* __restrict__ offsets, int* __restrict__ cursor,
                                                  int* __restrict__ rowtok, float* __restrict__ roww) {
    int i = blockIdx.x * 256 + threadIdx.x;
    if (i >= TK) return;
    int e = sel[i];
    int t = i >> 3;
    int p = atomicAdd(&cursor[e], 1);
    if (p < CAP) {
        int idx = offsets[e] + p;
        rowtok[idx] = t;
        roww[idx] = wts[i];
    }
}

// ---------------- prep: x fp32 -> bf16 ----------------
__global__ __launch_bounds__(256) void xconv_k(const float* __restrict__ in, bf16* __restrict__ out) {
    int i = blockIdx.x * 256 + threadIdx.x;
    float4 a = *(const float4*)(in + (size_t)i * 8);
    float4 b = *(const float4*)(in + (size_t)i * 8 + 4);
    bf16x8 v;
    v[0] = (bf16)a.x; v[1] = (bf16)a.y; v[2] = (bf16)a.z; v[3] = (bf16)a.w;
    v[4] = (bf16)b.x; v[5] = (bf16)b.y; v[6] = (bf16)b.z; v[7] = (bf16)b.w;
    *(bf16x8*)(out + (size_t)i * 8) = v;
}

// ---------------- prep: per-expert transpose + convert: in [E][R][C] f32 -> out [E][C][R] bf16 ----------------
__global__ __launch_bounds__(256) void tconv_k(const float* __restrict__ in, bf16* __restrict__ out, int R, int C) {
    __shared__ float tile[64][65];
    int e = blockIdx.z;
    int r0 = blockIdx.x * 64, c0 = blockIdx.y * 64;
    int t = threadIdx.x;
    int rr = t >> 4, cc = (t & 15) * 4;
    const float* src = in + ((size_t)e * R + r0) * C + c0;
    #pragma unroll
    for (int j = 0; j < 4; ++j) {
        float4 v = *(const float4*)(src + (size_t)(rr + 16 * j) * C + cc);
        tile[rr + 16 * j][cc + 0] = v.x;
        tile[rr + 16 * j][cc + 1] = v.y;
        tile[rr + 16 * j][cc + 2] = v.z;
        tile[rr + 16 * j][cc + 3] = v.w;
    }
    __syncthreads();
    bf16* dst = out + ((size_t)e * C + c0) * R + r0;
    #pragma unroll
    for (int j = 0; j < 4; ++j) {
        int oc = rr + 16 * j;   // row of output tile = original column
        bf16x4 v;
        v[0] = (bf16)tile[cc + 0][oc];
        v[1] = (bf16)tile[cc + 1][oc];
        v[2] = (bf16)tile[cc + 2][oc];
        v[3] = (bf16)tile[cc + 3][oc];
        *(bf16x4*)(dst + (size_t)oc * R + cc) = v;
    }
}

// ---------------- async global->LDS helper (16B per lane, dest = wave-uniform base + lane*16) ----------------
__device__ __forceinline__ void gll16(const bf16* g, bf16* l) {
    __builtin_amdgcn_global_load_lds((const __attribute__((address_space(1))) void*)g,
                                     (__attribute__((address_space(3))) void*)l, 16, 0, 0);
}

// ---------------- GEMM1: fused gate+up, bf16, global_load_lds, 2-phase dbuf, XCD-chunked grid ----------------
// 1D grid 1536 blocks -> (m in 0..7, n0 in {0,128,256}, e in 0..63); all 8 m-blocks of one
// (n0,e) pair land on the SAME XCD so the B panel is fetched once per XCD L2.
__global__ __launch_bounds__(256) void gemm_gu2_k(
        const bf16* __restrict__ xb, const bf16* __restrict__ WgT, const bf16* __restrict__ WuT,
        const int* __restrict__ rowtok, const int* __restrict__ offsets, const int* __restrict__ counts,
        bf16* __restrict__ Abuf) {
    int bid = blockIdx.x;
    int xcd = bid & 7;
    int i5  = bid >> 3;                  // [0,192)
    int pair = xcd * 24 + (i5 >> 3);     // [0,192) = 3 ntiles * 64 experts
    int m0 = (i5 & 7) * 128;
    int n0 = (pair % 3) * 128;
    int e  = pair / 3;
    int cnt = counts[e]; if (cnt > CAP) cnt = CAP;
    if (cnt == 0 || m0 >= cnt) return;
    int base = offsets[e];

    __shared__ __align__(16) bf16 As[2][128 * 32];
    __shared__ __align__(16) bf16 Bgs[2][128 * 32];
    __shared__ __align__(16) bf16 Bus[2][128 * 32];

    int tid = threadIdx.x, lane = tid & 63, wv = tid >> 6;

    // staging geometry: LDS tile linear [128 rows][32 k] bf16; wave wv issue i covers rows
    // half*16..+15 (half = wv*2+i); lane l -> row half*16+(l>>2), k-seg (l&3)*8.
    const bf16 *pa[2], *pg[2], *pu[2];
    int lofs[2];
    #pragma unroll
    for (int i = 0; i < 2; ++i) {
        int half = wv * 2 + i;
        int row  = half * 16 + (lane >> 2);
        int ks   = (lane & 3) * 8;
        int mr = m0 + row; if (mr >= cnt) mr = cnt - 1;
        pa[i] = xb  + (size_t)rowtok[base + mr] * DIM + ks;
        pg[i] = WgT + ((size_t)e * HD + n0 + row) * DIM + ks;
        pu[i] = WuT + ((size_t)e * HD + n0 + row) * DIM + ks;
        lofs[i] = half * 512;
    }

    int mo = (wv & 1) * 64, no = (wv >> 1) * 64;
    int fr = lane & 15, fq = lane >> 4;

    f32x4 ag[4][4], au[4][4];
    #pragma unroll
    for (int i = 0; i < 4; ++i)
        #pragma unroll
        for (int j = 0; j < 4; ++j)
            #pragma unroll
            for (int r = 0; r < 4; ++r) { ag[i][j][r] = 0.f; au[i][j][r] = 0.f; }

    // prologue: stage K-tile 0 into buffer 0
    #pragma unroll
    for (int i = 0; i < 2; ++i) {
        gll16(pa[i], &As[0][lofs[i]]);
        gll16(pg[i], &Bgs[0][lofs[i]]);
        gll16(pu[i], &Bus[0][lofs[i]]);
    }
    __syncthreads();

    const int NT = DIM / 32;   // 48
    for (int t = 0; t < NT; ++t) {
        int cur = t & 1, nxt = cur ^ 1;
        if (t + 1 < NT) {      // prefetch next K-tile into other buffer
            int k0 = (t + 1) * 32;
            #pragma unroll
            for (int i = 0; i < 2; ++i) {
                gll16(pa[i] + k0, &As[nxt][lofs[i]]);
                gll16(pg[i] + k0, &Bgs[nxt][lofs[i]]);
                gll16(pu[i] + k0, &Bus[nxt][lofs[i]]);
            }
        }
        bf16x8 af[4], bgf[4], buf_[4];
        #pragma unroll
        for (int i = 0; i < 4; ++i) {
            af[i]   = *(const bf16x8*)&As[cur][(mo + i * 16 + fr) * 32 + fq * 8];
            bgf[i]  = *(const bf16x8*)&Bgs[cur][(no + i * 16 + fr) * 32 + fq * 8];
            buf_[i] = *(const bf16x8*)&Bus[cur][(no + i * 16 + fr) * 32 + fq * 8];
        }
        #pragma unroll
        for (int i = 0; i < 4; ++i)
            #pragma unroll
            for (int j = 0; j < 4; ++j) {
                ag[i][j] = __builtin_amdgcn_mfma_f32_16x16x32_bf16(af[i], bgf[j], ag[i][j], 0, 0, 0);
                au[i][j] = __builtin_amdgcn_mfma_f32_16x16x32_bf16(af[i], buf_[j], au[i][j], 0, 0, 0);
            }
        __syncthreads();   // drains own-wave vmcnt (prefetch landed) + protects cur reuse
    }
    #pragma unroll
    for (int i = 0; i < 4; ++i) {
        #pragma unroll
        for (int j = 0; j < 4; ++j) {
            int col = n0 + no + j * 16 + fr;
            #pragma unroll
            for (int r = 0; r < 4; ++r) {
                int gm = m0 + mo + i * 16 + fq * 4 + r;
                if (gm < cnt) {
                    float g = ag[i][j][r], u = au[i][j][r];
                    float sg = g / (1.f + __expf(-g));   // silu
                    Abuf[(size_t)(base + gm) * HD + col] = (bf16)(sg * u);
                }
            }
        }
    }
}

// ---------------- GEMM2: down projection, bf16, 2-phase dbuf, XCD-chunked grid ----------------
// 1D grid 6144 blocks -> (m 0..7, n0 0..11, e 0..63)
__global__ __launch_bounds__(256) void gemm_dn2_k(
        const bf16* __restrict__ Abuf, const bf16* __restrict__ WdT,
        const int* __restrict__ rowtok, const float* __restrict__ roww,
        const int* __restrict__ offsets, const int* __restrict__ counts,
        float* __restrict__ out) {
    int bid = blockIdx.x;
    int xcd = bid & 7;
    int i5  = bid >> 3;                  // [0,768)
    int pair = xcd * 96 + (i5 >> 3);     // [0,768) = 12 ntiles * 64 experts
    int m0 = (i5 & 7) * 128;
    int n0 = (pair % 12) * 128;
    int e  = pair / 12;
    int cnt = counts[e]; if (cnt > CAP) cnt = CAP;
    if (cnt == 0 || m0 >= cnt) return;
    int base = offsets[e];

    __shared__ __align__(16) bf16 As[2][128 * 32];
    __shared__ __align__(16) bf16 Bs[2][128 * 32];

    int tid = threadIdx.x, lane = tid & 63, wv = tid >> 6;
    const bf16 *pa[2], *pb[2];
    int lofs[2];
    #pragma unroll
    for (int i = 0; i < 2; ++i) {
        int half = wv * 2 + i;
        int row  = half * 16 + (lane >> 2);
        int ks   = (lane & 3) * 8;
        int mr = m0 + row; if (mr >= cnt) mr = cnt - 1;
        pa[i] = Abuf + (size_t)(base + mr) * HD + ks;
        pb[i] = WdT  + ((size_t)e * DIM + n0 + row) * HD + ks;
        lofs[i] = half * 512;
    }

    int mo = (wv & 1) * 64, no = (wv >> 1) * 64;
    int fr = lane & 15, fq = lane >> 4;

    f32x4 acc[4][4];
    #pragma unroll
    for (int i = 0; i < 4; ++i)
        #pragma unroll
        for (int j = 0; j < 4; ++j)
            #pragma unroll
            for (int r = 0; r < 4; ++r) acc[i][j][r] = 0.f;

    #pragma unroll
    for (int i = 0; i < 2; ++i) {
        gll16(pa[i], &As[0][lofs[i]]);
        gll16(pb[i], &Bs[0][lofs[i]]);
    }
    __syncthreads();

    const int NT = HD / 32;   // 12
    for (int t = 0; t < NT; ++t) {
        int cur = t & 1, nxt = cur ^ 1;
        if (t + 1 < NT) {
            int k0 = (t + 1) * 32;
            #pragma unroll
            for (int i = 0; i < 2; ++i) {
                gll16(pa[i] + k0, &As[nxt][lofs[i]]);
                gll16(pb[i] + k0, &Bs[nxt][lofs[i]]);
            }
        }
        bf16x8 af[4], bf[4];
        #pragma unroll
        for (int i = 0; i < 4; ++i) {
            af[i] = *(const bf16x8*)&As[cur][(mo + i * 16 + fr) * 32 + fq * 8];
            bf[i] = *(const bf16x8*)&Bs[cur][(no + i * 16 + fr) * 32 + fq * 8];
        }
        #pragma unroll
        for (int i = 0; i < 4; ++i)
            #pragma unroll
            for (int j = 0; j < 4; ++j)
                acc[i][j] = __builtin_amdgcn_mfma_f32_16x16x32_bf16(af[i], bf[j], acc[i][j], 0, 0, 0);
        __syncthreads();
    }
    #pragma unroll
    for (int i = 0; i < 4; ++i) {
        #pragma unroll
        for (int r = 0; r < 4; ++r) {
            int gm = m0 + mo + i * 16 + fq * 4 + r;
            if (gm < cnt) {
                int tok = rowtok[base + gm];
                float w = roww[base + gm];
                float* po = out + (size_t)tok * DIM + n0 + no + fr;
                #pragma unroll
                for (int j = 0; j < 4; ++j)
                    atomicAdd(po + j * 16, acc[i][j][r] * w);
            }
        }
    }
}

// ================= fallback path (old fp32-staging kernels) — used if workspace too small =================
__device__ __forceinline__ bf16x8 pack8(const float* f) {
    bf16x8 v;
    #pragma unroll
    for (int j = 0; j < 8; ++j) v[j] = (bf16)f[j];
    return v;
}

__global__ __launch_bounds__(256) void gemm_gu_k(
        const float* __restrict__ x, const float* __restrict__ Wg, const float* __restrict__ Wu,
        const int* __restrict__ rowtok, const int* __restrict__ offsets, const int* __restrict__ counts,
        bf16* __restrict__ Abuf) {
    int e = blockIdx.z;
    int cnt = counts[e]; if (cnt > CAP) cnt = CAP;
    int m0 = blockIdx.x * 128;
    if (cnt == 0 || m0 >= cnt) return;
    int base = offsets[e];
    int n0 = blockIdx.y * 128;

    __shared__ __align__(16) bf16 As[128 * 32];
    __shared__ __align__(16) bf16 Bgs[128 * 32];
    __shared__ __align__(16) bf16 Bus[128 * 32];

    int tid = threadIdx.x;
    int arow = tid >> 1, aseg = (tid & 1) * 16;
    int mrow = m0 + arow; if (mrow >= cnt) mrow = cnt - 1;
    const float* pA = x + (size_t)rowtok[base + mrow] * DIM + aseg;
    int bn = tid & 127;
    int bk = (tid >> 7) * 16;
    const float* pG = Wg + ((size_t)e * DIM + bk) * HD + (n0 + bn);
    const float* pU = Wu + ((size_t)e * DIM + bk) * HD + (n0 + bn);

    int lane = tid & 63, wv = tid >> 6;
    int mo = (wv & 1) * 64, no = (wv >> 1) * 64;
    int fr = lane & 15, fq = lane >> 4;

    f32x4 ag[4][4], au[4][4];
    #pragma unroll
    for (int i = 0; i < 4; ++i)
        #pragma unroll
        for (int j = 0; j < 4; ++j)
            #pragma unroll
            for (int r = 0; r < 4; ++r) { ag[i][j][r] = 0.f; au[i][j][r] = 0.f; }

    for (int k0 = 0; k0 < DIM; k0 += 32) {
        float av[16] __attribute__((aligned(16)));
        float gv[16] __attribute__((aligned(16)));
        float uv[16] __attribute__((aligned(16)));
        *(float4*)&av[0]  = *(const float4*)(pA + k0);
        *(float4*)&av[4]  = *(const float4*)(pA + k0 + 4);
        *(float4*)&av[8]  = *(const float4*)(pA + k0 + 8);
        *(float4*)&av[12] = *(const float4*)(pA + k0 + 12);
        #pragma unroll
        for (int j = 0; j < 16; ++j) {
            gv[j] = pG[(size_t)(k0 + j) * HD];
            uv[j] = pU[(size_t)(k0 + j) * HD];
        }
        __syncthreads();
        *(bf16x8*)&As[arow * 32 + aseg]      = pack8(&av[0]);
        *(bf16x8*)&As[arow * 32 + aseg + 8]  = pack8(&av[8]);
        *(bf16x8*)&Bgs[bn * 32 + bk]         = pack8(&gv[0]);
        *(bf16x8*)&Bgs[bn * 32 + bk + 8]     = pack8(&gv[8]);
        *(bf16x8*)&Bus[bn * 32 + bk]         = pack8(&uv[0]);
        *(bf16x8*)&Bus[bn * 32 + bk + 8]     = pack8(&uv[8]);
        __syncthreads();
        bf16x8 af[4], bgf[4], buf_[4];
        #pragma unroll
        for (int i = 0; i < 4; ++i) {
            af[i]   = *(const bf16x8*)&As[(mo + i * 16 + fr) * 32 + fq * 8];
            bgf[i]  = *(const bf16x8*)&Bgs[(no + i * 16 + fr) * 32 + fq * 8];
            buf_[i] = *(const bf16x8*)&Bus[(no + i * 16 + fr) * 32 + fq * 8];
        }
        #pragma unroll
        for (int i = 0; i < 4; ++i)
            #pragma unroll
            for (int j = 0; j < 4; ++j) {
                ag[i][j] = __builtin_amdgcn_mfma_f32_16x16x32_bf16(af[i], bgf[j], ag[i][j], 0, 0, 0);
                au[i][j] = __builtin_amdgcn_mfma_f32_16x16x32_bf16(af[i], buf_[j], au[i][j], 0, 0, 0);
            }
    }
    #pragma unroll
    for (int i = 0; i < 4; ++i) {
        #pragma unroll
        for (int j = 0; j < 4; ++j) {
            int col = n0 + no + j * 16 + fr;
            #pragma unroll
            for (int r = 0; r < 4; ++r) {
                int gm = m0 + mo + i * 16 + fq * 4 + r;
                if (gm < cnt) {
                    float g = ag[i][j][r], u = au[i][j][r];
                    float sg = g / (1.f + __expf(-g));
                    Abuf[(size_t)(base + gm) * HD + col] = (bf16)(sg * u);
                }
            }
        }
    }
}

__global__ __launch_bounds__(256) void gemm_dn_k(
        const bf16* __restrict__ Abuf, const float* __restrict__ Wd,
        const int* __restrict__ rowtok, const float* __restrict__ roww,
        const int* __restrict__ offsets, const int* __restrict__ counts,
        float* __restrict__ out) {
    int e = blockIdx.z;
    int cnt = counts[e]; if (cnt > CAP) cnt = CAP;
    int m0 = blockIdx.x * 128;
    if (cnt == 0 || m0 >= cnt) return;
    int base = offsets[e];
    int n0 = blockIdx.y * 128;

    __shared__ __align__(16) bf16 As[128 * 32];
    __shared__ __align__(16) bf16 Bs[128 * 32];

    int tid = threadIdx.x;
    int arow = tid >> 1, aseg = (tid & 1) * 16;
    int mrow = m0 + arow; if (mrow >= cnt) mrow = cnt - 1;
    const bf16* pA = Abuf + (size_t)(base + mrow) * HD + aseg;
    int bn = tid & 127;
    int bk = (tid >> 7) * 16;
    const float* pB = Wd + ((size_t)e * HD + bk) * DIM + (n0 + bn);

    int lane = tid & 63, wv = tid >> 6;
    int mo = (wv & 1) * 64, no = (wv >> 1) * 64;
    int fr = lane & 15, fq = lane >> 4;

    f32x4 acc[4][4];
    #pragma unroll
    for (int i = 0; i < 4; ++i)
        #pragma unroll
        for (int j = 0; j < 4; ++j)
            #pragma unroll
            for (int r = 0; r < 4; ++r) acc[i][j][r] = 0.f;

    for (int k0 = 0; k0 < HD; k0 += 32) {
        uint4 a0 = *(const uint4*)(pA + k0);
        uint4 a1 = *(const uint4*)(pA + k0 + 8);
        float bv[16] __attribute__((aligned(16)));
        #pragma unroll
        for (int j = 0; j < 16; ++j) bv[j] = pB[(size_t)(k0 + j) * DIM];
        __syncthreads();
        *(uint4*)&As[arow * 32 + aseg]     = a0;
        *(uint4*)&As[arow * 32 + aseg + 8] = a1;
        *(bf16x8*)&Bs[bn * 32 + bk]     = pack8(&bv[0]);
        *(bf16x8*)&Bs[bn * 32 + bk + 8] = pack8(&bv[8]);
        __syncthreads();
        bf16x8 af[4], bf[4];
        #pragma unroll
        for (int i = 0; i < 4; ++i) {
            af[i] = *(const bf16x8*)&As[(mo + i * 16 + fr) * 32 + fq * 8];
            bf[i] = *(const bf16x8*)&Bs[(no + i * 16 + fr) * 32 + fq * 8];
        }
        #pragma unroll
        for (int i = 0; i < 4; ++i)
            #pragma unroll
            for (int j = 0; j < 4; ++j)
                acc[i][j] = __builtin_amdgcn_mfma_f32_16x16x32_bf16(af[i], bf[j], acc[i][j], 0, 0, 0);
    }
    #pragma unroll
    for (int i = 0; i < 4; ++i) {
        #pragma unroll
        for (int r = 0; r < 4; ++r) {
            int gm = m0 + mo + i * 16 + fq * 4 + r;
            if (gm < cnt) {
                int tok = rowtok[base + gm];
                float w = roww[base + gm];
                float* po = out + (size_t)tok * DIM + n0 + no + fr;
                #pragma unroll
                for (int j = 0; j < 4; ++j)
                    atomicAdd(po + j * 16, acc[i][j][r] * w);
            }
        }
    }
}

extern "C" void kernel_launch(void* const* d_in, const int* in_sizes, int n_in,
                              void* d_out, int out_size, void* d_ws, size_t ws_size,
                              hipStream_t stream) {
    const float* x  = (const float*)d_in[0];
    const float* gw = (const float*)d_in[1];
    const float* Wg = (const float*)d_in[2];
    const float* Wu = (const float*)d_in[3];
    const float* Wd = (const float*)d_in[4];
    float* out = (float*)d_out;
    char* ws = (char*)d_ws;

    int*   counts  = (int*)(ws + 0);        // 64 ints
    int*   cursor  = (int*)(ws + 256);      // 64 ints
    int*   offsets = (int*)(ws + 512);      // 65 ints
    int*   sel     = (int*)(ws + 4096);                    // TK ints
    float* wts     = (float*)(ws + 4096 + 1 * 131072);
    int*   rowtok  = (int*)(ws + 4096 + 2 * 131072);
    float* roww    = (float*)(ws + 4096 + 3 * 131072);
    bf16*  AbufOld = (bf16*)(ws + 4096 + 4 * 131072);      // fallback layout (25.2 MB)

    // big-workspace layout for the bf16 fast path
    size_t o = (size_t)1 << 20;
    bf16* Abuf = (bf16*)(ws + o); o += (size_t)TK * HD * 2;         // 25.2 MB
    bf16* xb   = (bf16*)(ws + o); o += (size_t)T_TOK * DIM * 2;     // 12.6 MB
    bf16* WgT  = (bf16*)(ws + o); o += (size_t)NE * HD * DIM * 2;   // 75.5 MB
    bf16* WuT  = (bf16*)(ws + o); o += (size_t)NE * HD * DIM * 2;   // 75.5 MB
    bf16* WdT  = (bf16*)(ws + o); o += (size_t)NE * DIM * HD * 2;   // 75.5 MB
    bool big = ws_size >= o;                                        // ~265.3 MB

    hipMemsetAsync(ws, 0, 1024, stream);
    hipMemsetAsync(d_out, 0, (size_t)out_size * sizeof(float), stream);
    router_k<<<T_TOK / 16, 256, 0, stream>>>(x, gw, sel, wts, counts);
    scan_k<<<1, 64, 0, stream>>>(counts, offsets);
    dispatch_k<<<TK / 256, 256, 0, stream>>>(sel, wts, offsets, cursor, rowtok, roww);

    if (big) {
        xconv_k<<<(T_TOK * DIM / 8) / 256, 256, 0, stream>>>(x, xb);
        tconv_k<<<dim3(DIM / 64, HD / 64, NE), 256, 0, stream>>>(Wg, WgT, DIM, HD);
        tconv_k<<<dim3(DIM / 64, HD / 64, NE), 256, 0, stream>>>(Wu, WuT, DIM, HD);
        tconv_k<<<dim3(HD / 64, DIM / 64, NE), 256, 0, stream>>>(Wd, WdT, HD, DIM);
        gemm_gu2_k<<<8 * 3 * NE, 256, 0, stream>>>(xb, WgT, WuT, rowtok, offsets, counts, Abuf);
        gemm_dn2_k<<<8 * 12 * NE, 256, 0, stream>>>(Abuf, WdT, rowtok, roww, offsets, counts, out);
    } else {
        gemm_gu_k<<<dim3(CAP / 128, HD / 128, NE), 256, 0, stream>>>(x, Wg, Wu, rowtok, offsets, counts, AbufOld);
        gemm_dn_k<<<dim3(CAP / 128, DIM / 128, NE), 256, 0, stream>>>(AbufOld, Wd, rowtok, roww, offsets, counts, out);
    }
}

// Round 3
// 1054.656 us; speedup vs baseline: 1.2342x; 1.0372x over previous
//
#include <hip/hip_runtime.h>
#include <stdint.h>

typedef __bf16 bf16;
typedef __attribute__((ext_vector_type(8))) __bf16 bf16x8;
typedef __attribute__((ext_vector_type(4))) __bf16 bf16x4;
typedef __attribute__((ext_vector_type(4))) float f32x4;

#define T_TOK 4096
#define DIM   1536
#define NE    64
#define HD    384
#define TOPK  8
#define CAP   1024
#define TK    32768   // T_TOK*TOPK

// ---------------- fused router: fp32 logits -> softmax -> top8 -> renorm ----------------
__global__ __launch_bounds__(256) void router_k(const float* __restrict__ x, const float* __restrict__ gw,
                                                int* __restrict__ sel, float* __restrict__ wts,
                                                int* __restrict__ counts) {
    __shared__ float xs[16][DIM];     // 98304 B
    __shared__ float lgs[16][NE];     // 4096 B
    int t0 = blockIdx.x * 16;
    int tid = threadIdx.x;
    {
        const float4* src = (const float4*)(x + (size_t)t0 * DIM);
        float4* dst = (float4*)&xs[0][0];
        for (int i = tid; i < 16 * DIM / 4; i += 256) dst[i] = src[i];
    }
    __syncthreads();
    int lane = tid & 63, wv = tid >> 6;
    for (int ee = 0; ee < 16; ++ee) {
        int e = wv * 16 + ee;
        const float2* g2 = (const float2*)(gw + (size_t)e * DIM);
        float acc[16];
        #pragma unroll
        for (int t = 0; t < 16; ++t) acc[t] = 0.f;
        #pragma unroll
        for (int it = 0; it < DIM / 128; ++it) {
            float2 gv = g2[lane + 64 * it];
            #pragma unroll
            for (int t = 0; t < 16; ++t) {
                float2 xv = *(const float2*)&xs[t][2 * (lane + 64 * it)];
                acc[t] += gv.x * xv.x + gv.y * xv.y;
            }
        }
        #pragma unroll
        for (int t = 0; t < 16; ++t) {
            float a = acc[t];
            #pragma unroll
            for (int off = 32; off; off >>= 1) a += __shfl_xor(a, off, 64);
            if (lane == 0) lgs[t][e] = a;
        }
    }
    __syncthreads();
    for (int q = 0; q < 4; ++q) {
        int tt = wv * 4 + q;
        int t = t0 + tt;
        float l = lgs[tt][lane];
        float m = l;
        #pragma unroll
        for (int off = 32; off; off >>= 1) m = fmaxf(m, __shfl_xor(m, off, 64));
        float p = __expf(l - m);
        float s = p;
        #pragma unroll
        for (int off = 32; off; off >>= 1) s += __shfl_xor(s, off, 64);
        p /= s;
        float cur = p;
        float psum = 0.f;
        float myv = 0.f; int myi = 0;
        #pragma unroll
        for (int k = 0; k < 8; ++k) {
            float v = cur; int idx = lane;
            #pragma unroll
            for (int off = 32; off; off >>= 1) {
                float ov = __shfl_xor(v, off, 64);
                int   oi = __shfl_xor(idx, off, 64);
                if (ov > v || (ov == v && oi < idx)) { v = ov; idx = oi; }
            }
            psum += v;
            if (lane == k) { myv = v; myi = idx; }
            if (lane == idx) cur = -1.f;
        }
        if (lane < 8) {
            sel[t * TOPK + lane] = myi;
            wts[t * TOPK + lane] = myv / psum;
            atomicAdd(&counts[myi], 1);
        }
    }
}

// ---------------- exclusive scan over 64 counts (capped at CAP) ----------------
__global__ void scan_k(const int* __restrict__ counts, int* __restrict__ offsets) {
    if (threadIdx.x == 0) {
        int s = 0;
        for (int e = 0; e < NE; ++e) {
            offsets[e] = s;
            int c = counts[e]; if (c > CAP) c = CAP;
            s += c;
        }
        offsets[NE] = s;
    }
}

// ---------------- compact assignments by expert ----------------
__global__ __launch_bounds__(256) void dispatch_k(const int* __restrict__ sel, const float* __restrict__ wts,
                                                  const int* __restrict__ offsets, int* __restrict__ cursor,
                                                  int* __restrict__ rowtok, float* __restrict__ roww) {
    int i = blockIdx.x * 256 + threadIdx.x;
    if (i >= TK) return;
    int e = sel[i];
    int t = i >> 3;
    int p = atomicAdd(&cursor[e], 1);
    if (p < CAP) {
        int idx = offsets[e] + p;
        rowtok[idx] = t;
        roww[idx] = wts[i];
    }
}

// ---------------- prep: x fp32 -> bf16 ----------------
__global__ __launch_bounds__(256) void xconv_k(const float* __restrict__ in, bf16* __restrict__ out) {
    int i = blockIdx.x * 256 + threadIdx.x;
    float4 a = *(const float4*)(in + (size_t)i * 8);
    float4 b = *(const float4*)(in + (size_t)i * 8 + 4);
    bf16x8 v;
    v[0] = (bf16)a.x; v[1] = (bf16)a.y; v[2] = (bf16)a.z; v[3] = (bf16)a.w;
    v[4] = (bf16)b.x; v[5] = (bf16)b.y; v[6] = (bf16)b.z; v[7] = (bf16)b.w;
    *(bf16x8*)(out + (size_t)i * 8) = v;
}

// ---------------- prep: per-expert transpose + convert: in [E][R][C] f32 -> out [E][C][R] bf16 ----------------
// 64x64 tile; [64][68] f32 LDS (aligned float4 writes); output via 8 scalar LDS reads (2-way banks)
// + one bf16x8 16B store per task (2 tasks/thread).
__global__ __launch_bounds__(256) void tconv_k(const float* __restrict__ in, bf16* __restrict__ out, int R, int C) {
    __shared__ float tile[64][68];
    int e = blockIdx.z;
    int r0 = blockIdx.x * 64, c0 = blockIdx.y * 64;
    int t = threadIdx.x;
    int rr = t >> 4, cc = (t & 15) * 4;
    const float* src = in + ((size_t)e * R + r0) * C + c0;
    #pragma unroll
    for (int j = 0; j < 4; ++j) {
        float4 v = *(const float4*)(src + (size_t)(rr + 16 * j) * C + cc);
        *(float4*)&tile[rr + 16 * j][cc] = v;
    }
    __syncthreads();
    bf16* dst = out + ((size_t)e * C + c0) * R + r0;
    int rseg = (t & 7) * 8;           // 8 consecutive original-rows
    #pragma unroll
    for (int p = 0; p < 2; ++p) {
        int oc = (t >> 3) + 32 * p;   // output row = original column
        bf16x8 v;
        #pragma unroll
        for (int k = 0; k < 8; ++k) v[k] = (bf16)tile[rseg + k][oc];
        *(bf16x8*)(dst + (size_t)oc * R + rseg) = v;
    }
}

// ---------------- async global->LDS helper (16B per lane, dest = wave-uniform base + lane*16) ----------------
__device__ __forceinline__ void gll16(const bf16* g, bf16* l) {
    __builtin_amdgcn_global_load_lds((const __attribute__((address_space(1))) void*)g,
                                     (__attribute__((address_space(3))) void*)l, 16, 0, 0);
}

// ---------------- GEMM1: fused gate+up, bf16, counted-vmcnt dbuf pipeline, XCD-chunked grid ----------------
// 1D grid 1536 blocks -> (m 0..7, n0 {0,128,256}, e 0..63); all 8 m-blocks of one (n0,e) on same XCD.
__global__ __launch_bounds__(256) void gemm_gu2_k(
        const bf16* __restrict__ xb, const bf16* __restrict__ WgT, const bf16* __restrict__ WuT,
        const int* __restrict__ rowtok, const int* __restrict__ offsets, const int* __restrict__ counts,
        bf16* __restrict__ Abuf) {
    int bid = blockIdx.x;
    int xcd = bid & 7;
    int i5  = bid >> 3;                  // [0,192)
    int pair = xcd * 24 + (i5 >> 3);     // [0,192) = 3 ntiles * 64 experts
    int m0 = (i5 & 7) * 128;
    int n0 = (pair % 3) * 128;
    int e  = pair / 3;
    int cnt = counts[e]; if (cnt > CAP) cnt = CAP;
    if (cnt == 0 || m0 >= cnt) return;
    int base = offsets[e];

    __shared__ __align__(16) bf16 As[2][128 * 32];
    __shared__ __align__(16) bf16 Bgs[2][128 * 32];
    __shared__ __align__(16) bf16 Bus[2][128 * 32];

    int tid = threadIdx.x, lane = tid & 63, wv = tid >> 6;

    const bf16 *pa[2], *pg[2], *pu[2];
    int lofs[2];
    #pragma unroll
    for (int i = 0; i < 2; ++i) {
        int half = wv * 2 + i;
        int row  = half * 16 + (lane >> 2);
        int ks   = (lane & 3) * 8;
        int mr = m0 + row; if (mr >= cnt) mr = cnt - 1;
        pa[i] = xb  + (size_t)rowtok[base + mr] * DIM + ks;
        pg[i] = WgT + ((size_t)e * HD + n0 + row) * DIM + ks;
        pu[i] = WuT + ((size_t)e * HD + n0 + row) * DIM + ks;
        lofs[i] = half * 512;
    }

    int mo = (wv & 1) * 64, no = (wv >> 1) * 64;
    int fr = lane & 15, fq = lane >> 4;

    f32x4 ag[4][4], au[4][4];
    #pragma unroll
    for (int i = 0; i < 4; ++i)
        #pragma unroll
        for (int j = 0; j < 4; ++j)
            #pragma unroll
            for (int r = 0; r < 4; ++r) { ag[i][j][r] = 0.f; au[i][j][r] = 0.f; }

    // prologue: stage K-tile 0 into buffer 0 (6 loads in flight)
    #pragma unroll
    for (int i = 0; i < 2; ++i) {
        gll16(pa[i], &As[0][lofs[i]]);
        gll16(pg[i], &Bgs[0][lofs[i]]);
        gll16(pu[i], &Bus[0][lofs[i]]);
    }

    const int NT = DIM / 32;   // 48
    for (int t = 0; t < NT; ++t) {
        const int cur = t & 1;
        if (t + 1 < NT) {
            const int nxt = cur ^ 1;
            const int k0 = (t + 1) * 32;
            #pragma unroll
            for (int i = 0; i < 2; ++i) {
                gll16(pa[i] + k0, &As[nxt][lofs[i]]);
                gll16(pg[i] + k0, &Bgs[nxt][lofs[i]]);
                gll16(pu[i] + k0, &Bus[nxt][lofs[i]]);
            }
            // wait only the PREVIOUS tile's 6 loads; leave the 6 just issued in flight
            asm volatile("s_waitcnt vmcnt(6)" ::: "memory");
        } else {
            asm volatile("s_waitcnt vmcnt(0)" ::: "memory");
        }
        __builtin_amdgcn_s_barrier();          // buf cur is ready for all waves
        bf16x8 af[4], bgf[4], buf_[4];
        #pragma unroll
        for (int i = 0; i < 4; ++i) {
            af[i]   = *(const bf16x8*)&As[cur][(mo + i * 16 + fr) * 32 + fq * 8];
            bgf[i]  = *(const bf16x8*)&Bgs[cur][(no + i * 16 + fr) * 32 + fq * 8];
            buf_[i] = *(const bf16x8*)&Bus[cur][(no + i * 16 + fr) * 32 + fq * 8];
        }
        #pragma unroll
        for (int i = 0; i < 4; ++i)
            #pragma unroll
            for (int j = 0; j < 4; ++j) {
                ag[i][j] = __builtin_amdgcn_mfma_f32_16x16x32_bf16(af[i], bgf[j], ag[i][j], 0, 0, 0);
                au[i][j] = __builtin_amdgcn_mfma_f32_16x16x32_bf16(af[i], buf_[j], au[i][j], 0, 0, 0);
            }
        asm volatile("s_waitcnt lgkmcnt(0)" ::: "memory");   // my reads of cur are done
        __builtin_amdgcn_s_barrier();          // safe for next iter to overwrite cur
    }
    #pragma unroll
    for (int i = 0; i < 4; ++i) {
        #pragma unroll
        for (int j = 0; j < 4; ++j) {
            int col = n0 + no + j * 16 + fr;
            #pragma unroll
            for (int r = 0; r < 4; ++r) {
                int gm = m0 + mo + i * 16 + fq * 4 + r;
                if (gm < cnt) {
                    float g = ag[i][j][r], u = au[i][j][r];
                    float sg = g / (1.f + __expf(-g));   // silu
                    Abuf[(size_t)(base + gm) * HD + col] = (bf16)(sg * u);
                }
            }
        }
    }
}

// ---------------- GEMM2: down projection, bf16, counted-vmcnt dbuf pipeline, XCD-chunked grid ----------------
// 1D grid 6144 blocks -> (m 0..7, n0 0..11, e 0..63); all tiles of one expert on same XCD.
__global__ __launch_bounds__(256) void gemm_dn2_k(
        const bf16* __restrict__ Abuf, const bf16* __restrict__ WdT,
        const int* __restrict__ rowtok, const float* __restrict__ roww,
        const int* __restrict__ offsets, const int* __restrict__ counts,
        float* __restrict__ out) {
    int bid = blockIdx.x;
    int xcd = bid & 7;
    int i5  = bid >> 3;                  // [0,768)
    int pair = xcd * 96 + (i5 >> 3);     // [0,768) = 12 ntiles * 64 experts
    int m0 = (i5 & 7) * 128;
    int n0 = (pair % 12) * 128;
    int e  = pair / 12;
    int cnt = counts[e]; if (cnt > CAP) cnt = CAP;
    if (cnt == 0 || m0 >= cnt) return;
    int base = offsets[e];

    __shared__ __align__(16) bf16 As[2][128 * 32];
    __shared__ __align__(16) bf16 Bs[2][128 * 32];

    int tid = threadIdx.x, lane = tid & 63, wv = tid >> 6;
    const bf16 *pa[2], *pb[2];
    int lofs[2];
    #pragma unroll
    for (int i = 0; i < 2; ++i) {
        int half = wv * 2 + i;
        int row  = half * 16 + (lane >> 2);
        int ks   = (lane & 3) * 8;
        int mr = m0 + row; if (mr >= cnt) mr = cnt - 1;
        pa[i] = Abuf + (size_t)(base + mr) * HD + ks;
        pb[i] = WdT  + ((size_t)e * DIM + n0 + row) * HD + ks;
        lofs[i] = half * 512;
    }

    int mo = (wv & 1) * 64, no = (wv >> 1) * 64;
    int fr = lane & 15, fq = lane >> 4;

    f32x4 acc[4][4];
    #pragma unroll
    for (int i = 0; i < 4; ++i)
        #pragma unroll
        for (int j = 0; j < 4; ++j)
            #pragma unroll
            for (int r = 0; r < 4; ++r) acc[i][j][r] = 0.f;

    #pragma unroll
    for (int i = 0; i < 2; ++i) {
        gll16(pa[i], &As[0][lofs[i]]);
        gll16(pb[i], &Bs[0][lofs[i]]);
    }

    const int NT = HD / 32;   // 12
    for (int t = 0; t < NT; ++t) {
        const int cur = t & 1;
        if (t + 1 < NT) {
            const int nxt = cur ^ 1;
            const int k0 = (t + 1) * 32;
            #pragma unroll
            for (int i = 0; i < 2; ++i) {
                gll16(pa[i] + k0, &As[nxt][lofs[i]]);
                gll16(pb[i] + k0, &Bs[nxt][lofs[i]]);
            }
            asm volatile("s_waitcnt vmcnt(4)" ::: "memory");
        } else {
            asm volatile("s_waitcnt vmcnt(0)" ::: "memory");
        }
        __builtin_amdgcn_s_barrier();
        bf16x8 af[4], bf[4];
        #pragma unroll
        for (int i = 0; i < 4; ++i) {
            af[i] = *(const bf16x8*)&As[cur][(mo + i * 16 + fr) * 32 + fq * 8];
            bf[i] = *(const bf16x8*)&Bs[cur][(no + i * 16 + fr) * 32 + fq * 8];
        }
        #pragma unroll
        for (int i = 0; i < 4; ++i)
            #pragma unroll
            for (int j = 0; j < 4; ++j)
                acc[i][j] = __builtin_amdgcn_mfma_f32_16x16x32_bf16(af[i], bf[j], acc[i][j], 0, 0, 0);
        asm volatile("s_waitcnt lgkmcnt(0)" ::: "memory");
        __builtin_amdgcn_s_barrier();
    }
    #pragma unroll
    for (int i = 0; i < 4; ++i) {
        #pragma unroll
        for (int r = 0; r < 4; ++r) {
            int gm = m0 + mo + i * 16 + fq * 4 + r;
            if (gm < cnt) {
                int tok = rowtok[base + gm];
                float w = roww[base + gm];
                float* po = out + (size_t)tok * DIM + n0 + no + fr;
                #pragma unroll
                for (int j = 0; j < 4; ++j)
                    atomicAdd(po + j * 16, acc[i][j][r] * w);
            }
        }
    }
}

// ================= fallback path (old fp32-staging kernels) — used if workspace too small =================
__device__ __forceinline__ bf16x8 pack8(const float* f) {
    bf16x8 v;
    #pragma unroll
    for (int j = 0; j < 8; ++j) v[j] = (bf16)f[j];
    return v;
}

__global__ __launch_bounds__(256) void gemm_gu_k(
        const float* __restrict__ x, const float* __restrict__ Wg, const float* __restrict__ Wu,
        const int* __restrict__ rowtok, const int* __restrict__ offsets, const int* __restrict__ counts,
        bf16* __restrict__ Abuf) {
    int e = blockIdx.z;
    int cnt = counts[e]; if (cnt > CAP) cnt = CAP;
    int m0 = blockIdx.x * 128;
    if (cnt == 0 || m0 >= cnt) return;
    int base = offsets[e];
    int n0 = blockIdx.y * 128;

    __shared__ __align__(16) bf16 As[128 * 32];
    __shared__ __align__(16) bf16 Bgs[128 * 32];
    __shared__ __align__(16) bf16 Bus[128 * 32];

    int tid = threadIdx.x;
    int arow = tid >> 1, aseg = (tid & 1) * 16;
    int mrow = m0 + arow; if (mrow >= cnt) mrow = cnt - 1;
    const float* pA = x + (size_t)rowtok[base + mrow] * DIM + aseg;
    int bn = tid & 127;
    int bk = (tid >> 7) * 16;
    const float* pG = Wg + ((size_t)e * DIM + bk) * HD + (n0 + bn);
    const float* pU = Wu + ((size_t)e * DIM + bk) * HD + (n0 + bn);

    int lane = tid & 63, wv = tid >> 6;
    int mo = (wv & 1) * 64, no = (wv >> 1) * 64;
    int fr = lane & 15, fq = lane >> 4;

    f32x4 ag[4][4], au[4][4];
    #pragma unroll
    for (int i = 0; i < 4; ++i)
        #pragma unroll
        for (int j = 0; j < 4; ++j)
            #pragma unroll
            for (int r = 0; r < 4; ++r) { ag[i][j][r] = 0.f; au[i][j][r] = 0.f; }

    for (int k0 = 0; k0 < DIM; k0 += 32) {
        float av[16] __attribute__((aligned(16)));
        float gv[16] __attribute__((aligned(16)));
        float uv[16] __attribute__((aligned(16)));
        *(float4*)&av[0]  = *(const float4*)(pA + k0);
        *(float4*)&av[4]  = *(const float4*)(pA + k0 + 4);
        *(float4*)&av[8]  = *(const float4*)(pA + k0 + 8);
        *(float4*)&av[12] = *(const float4*)(pA + k0 + 12);
        #pragma unroll
        for (int j = 0; j < 16; ++j) {
            gv[j] = pG[(size_t)(k0 + j) * HD];
            uv[j] = pU[(size_t)(k0 + j) * HD];
        }
        __syncthreads();
        *(bf16x8*)&As[arow * 32 + aseg]      = pack8(&av[0]);
        *(bf16x8*)&As[arow * 32 + aseg + 8]  = pack8(&av[8]);
        *(bf16x8*)&Bgs[bn * 32 + bk]         = pack8(&gv[0]);
        *(bf16x8*)&Bgs[bn * 32 + bk + 8]     = pack8(&gv[8]);
        *(bf16x8*)&Bus[bn * 32 + bk]         = pack8(&uv[0]);
        *(bf16x8*)&Bus[bn * 32 + bk + 8]     = pack8(&uv[8]);
        __syncthreads();
        bf16x8 af[4], bgf[4], buf_[4];
        #pragma unroll
        for (int i = 0; i < 4; ++i) {
            af[i]   = *(const bf16x8*)&As[(mo + i * 16 + fr) * 32 + fq * 8];
            bgf[i]  = *(const bf16x8*)&Bgs[(no + i * 16 + fr) * 32 + fq * 8];
            buf_[i] = *(const bf16x8*)&Bus[(no + i * 16 + fr) * 32 + fq * 8];
        }
        #pragma unroll
        for (int i = 0; i < 4; ++i)
            #pragma unroll
            for (int j = 0; j < 4; ++j) {
                ag[i][j] = __builtin_amdgcn_mfma_f32_16x16x32_bf16(af[i], bgf[j], ag[i][j], 0, 0, 0);
                au[i][j] = __builtin_amdgcn_mfma_f32_16x16x32_bf16(af[i], buf_[j], au[i][j], 0, 0, 0);
            }
    }
    #pragma unroll
    for (int i = 0; i < 4; ++i) {
        #pragma unroll
        for (int j = 0; j < 4; ++j) {
            int col = n0 + no + j * 16 + fr;
            #pragma unroll
            for (int r = 0; r < 4; ++r) {
                int gm = m0 + mo + i * 16 + fq * 4 + r;
                if (gm < cnt) {
                    float g = ag[i][j][r], u = au[i][j][r];
                    float sg = g / (1.f + __expf(-g));
                    Abuf[(size_t)(base + gm) * HD + col] = (bf16)(sg * u);
                }
            }
        }
    }
}

__global__ __launch_bounds__(256) void gemm_dn_k(
        const bf16* __restrict__ Abuf, const float* __restrict__ Wd,
        const int* __restrict__ rowtok, const float* __restrict__ roww,
        const int* __restrict__ offsets, const int* __restrict__ counts,
        float* __restrict__ out) {
    int e = blockIdx.z;
    int cnt = counts[e]; if (cnt > CAP) cnt = CAP;
    int m0 = blockIdx.x * 128;
    if (cnt == 0 || m0 >= cnt) return;
    int base = offsets[e];
    int n0 = blockIdx.y * 128;

    __shared__ __align__(16) bf16 As[128 * 32];
    __shared__ __align__(16) bf16 Bs[128 * 32];

    int tid = threadIdx.x;
    int arow = tid >> 1, aseg = (tid & 1) * 16;
    int mrow = m0 + arow; if (mrow >= cnt) mrow = cnt - 1;
    const bf16* pA = Abuf + (size_t)(base + mrow) * HD + aseg;
    int bn = tid & 127;
    int bk = (tid >> 7) * 16;
    const float* pB = Wd + ((size_t)e * HD + bk) * DIM + (n0 + bn);

    int lane = tid & 63, wv = tid >> 6;
    int mo = (wv & 1) * 64, no = (wv >> 1) * 64;
    int fr = lane & 15, fq = lane >> 4;

    f32x4 acc[4][4];
    #pragma unroll
    for (int i = 0; i < 4; ++i)
        #pragma unroll
        for (int j = 0; j < 4; ++j)
            #pragma unroll
            for (int r = 0; r < 4; ++r) acc[i][j][r] = 0.f;

    for (int k0 = 0; k0 < HD; k0 += 32) {
        uint4 a0 = *(const uint4*)(pA + k0);
        uint4 a1 = *(const uint4*)(pA + k0 + 8);
        float bv[16] __attribute__((aligned(16)));
        #pragma unroll
        for (int j = 0; j < 16; ++j) bv[j] = pB[(size_t)(k0 + j) * DIM];
        __syncthreads();
        *(uint4*)&As[arow * 32 + aseg]     = a0;
        *(uint4*)&As[arow * 32 + aseg + 8] = a1;
        *(bf16x8*)&Bs[bn * 32 + bk]     = pack8(&bv[0]);
        *(bf16x8*)&Bs[bn * 32 + bk + 8] = pack8(&bv[8]);
        __syncthreads();
        bf16x8 af[4], bf[4];
        #pragma unroll
        for (int i = 0; i < 4; ++i) {
            af[i] = *(const bf16x8*)&As[(mo + i * 16 + fr) * 32 + fq * 8];
            bf[i] = *(const bf16x8*)&Bs[(no + i * 16 + fr) * 32 + fq * 8];
        }
        #pragma unroll
        for (int i = 0; i < 4; ++i)
            #pragma unroll
            for (int j = 0; j < 4; ++j)
                acc[i][j] = __builtin_amdgcn_mfma_f32_16x16x32_bf16(af[i], bf[j], acc[i][j], 0, 0, 0);
    }
    #pragma unroll
    for (int i = 0; i < 4; ++i) {
        #pragma unroll
        for (int r = 0; r < 4; ++r) {
            int gm = m0 + mo + i * 16 + fq * 4 + r;
            if (gm < cnt) {
                int tok = rowtok[base + gm];
                float w = roww[base + gm];
                float* po = out + (size_t)tok * DIM + n0 + no + fr;
                #pragma unroll
                for (int j = 0; j < 4; ++j)
                    atomicAdd(po + j * 16, acc[i][j][r] * w);
            }
        }
    }
}

extern "C" void kernel_launch(void* const* d_in, const int* in_sizes, int n_in,
                              void* d_out, int out_size, void* d_ws, size_t ws_size,
                              hipStream_t stream) {
    const float* x  = (const float*)d_in[0];
    const float* gw = (const float*)d_in[1];
    const float* Wg = (const float*)d_in[2];
    const float* Wu = (const float*)d_in[3];
    const float* Wd = (const float*)d_in[4];
    float* out = (float*)d_out;
    char* ws = (char*)d_ws;

    int*   counts  = (int*)(ws + 0);        // 64 ints
    int*   cursor  = (int*)(ws + 256);      // 64 ints
    int*   offsets = (int*)(ws + 512);      // 65 ints
    int*   sel     = (int*)(ws + 4096);                    // TK ints
    float* wts     = (float*)(ws + 4096 + 1 * 131072);
    int*   rowtok  = (int*)(ws + 4096 + 2 * 131072);
    float* roww    = (float*)(ws + 4096 + 3 * 131072);
    bf16*  AbufOld = (bf16*)(ws + 4096 + 4 * 131072);      // fallback layout (25.2 MB)

    // big-workspace layout for the bf16 fast path
    size_t o = (size_t)1 << 20;
    bf16* Abuf = (bf16*)(ws + o); o += (size_t)TK * HD * 2;         // 25.2 MB
    bf16* xb   = (bf16*)(ws + o); o += (size_t)T_TOK * DIM * 2;     // 12.6 MB
    bf16* WgT  = (bf16*)(ws + o); o += (size_t)NE * HD * DIM * 2;   // 75.5 MB
    bf16* WuT  = (bf16*)(ws + o); o += (size_t)NE * HD * DIM * 2;   // 75.5 MB
    bf16* WdT  = (bf16*)(ws + o); o += (size_t)NE * DIM * HD * 2;   // 75.5 MB
    bool big = ws_size >= o;                                        // ~265.3 MB

    hipMemsetAsync(ws, 0, 1024, stream);
    hipMemsetAsync(d_out, 0, (size_t)out_size * sizeof(float), stream);
    router_k<<<T_TOK / 16, 256, 0, stream>>>(x, gw, sel, wts, counts);
    scan_k<<<1, 64, 0, stream>>>(counts, offsets);
    dispatch_k<<<TK / 256, 256, 0, stream>>>(sel, wts, offsets, cursor, rowtok, roww);

    if (big) {
        xconv_k<<<(T_TOK * DIM / 8) / 256, 256, 0, stream>>>(x, xb);
        tconv_k<<<dim3(DIM / 64, HD / 64, NE), 256, 0, stream>>>(Wg, WgT, DIM, HD);
        tconv_k<<<dim3(DIM / 64, HD / 64, NE), 256, 0, stream>>>(Wu, WuT, DIM, HD);
        tconv_k<<<dim3(HD / 64, DIM / 64, NE), 256, 0, stream>>>(Wd, WdT, HD, DIM);
        gemm_gu2_k<<<8 * 3 * NE, 256, 0, stream>>>(xb, WgT, WuT, rowtok, offsets, counts, Abuf);
        gemm_dn2_k<<<8 * 12 * NE, 256, 0, stream>>>(Abuf, WdT, rowtok, roww, offsets, counts, out);
    } else {
        gemm_gu_k<<<dim3(CAP / 128, HD / 128, NE), 256, 0, stream>>>(x, Wg, Wu, rowtok, offsets, counts, AbufOld);
        gemm_dn_k<<<dim3(CAP / 128, DIM / 128, NE), 256, 0, stream>>>(AbufOld, Wd, rowtok, roww, offsets, counts, out);
    }
}